// Round 4
// baseline (143.731 us; speedup 1.0000x reference)
//
#include <hip/hip_runtime.h>
#include <stdint.h>

// OctonionLinear == GEMM: out[b, i*8+k] = sum_{j,p} x[b, j*8+p] * W[i,j,p,k] + bias[i,k]
// M=512, N=4096, K=4096, fp32 in/out, bf16 MFMA.
// R11: structural cut. R6/R7/R10 proved gemm schedule is NOT the critical path
//  (occupancy 17->62%, wave-shape 8x(64x32) vs 4x(64x64): all ~139us).
//  So: eliminate split-K machinery. KSPLIT=1, tile 64x64, grid 64x8=512 blocks
//  (2/CU, 8 waves/CU keeps cross-block overlap), each block owns its output
//  tile -> fused bias + direct out store. Deletes: part buffer (32MB write +
//  32MB read), reduce_kernel (+launch gap), bias-init prep segment.
//  2 launches total, ws = 36MB.
// prep: W-transpose + x-convert (unchanged, near HBM floor).

#define M_DIM 512
#define N_DIM 4096
#define K_DIM 4096
#define NIT (K_DIM / 32)  // 128

typedef __bf16 bf16x8 __attribute__((ext_vector_type(8)));
typedef float f32x4 __attribute__((ext_vector_type(4)));

__device__ inline unsigned short f2bf(float f) {
  union { float f; unsigned int u; } v;
  v.f = f;
  unsigned int u = v.u;
  unsigned int r = (u + 0x7fffu + ((u >> 16) & 1u)) >> 16;  // RNE
  return (unsigned short)r;
}

// blocks [0,4096): W transpose+convert -> bt[nn][kk], coalesced 16KB chunks.
// blocks [4096,5120): x convert -> abf, 8 el/thread.
__global__ __launch_bounds__(256) void prep_kernel(
    const float* __restrict__ x, const float* __restrict__ w,
    unsigned short* __restrict__ abf, unsigned short* __restrict__ bt) {
  const int bid = blockIdx.x;
  const int t = threadIdx.x;
  if (bid < 4096) {
    __shared__ __align__(16) unsigned short lT[8][512];  // [k][j'*8+p], 8KB
    const int i = bid >> 3;
    const int jg = bid & 7;
    const float4* src =
        (const float4*)(w + (size_t)i * 32768 + jg * 4096 + t * 16);
    float4 v0 = src[0], v1 = src[1], v2 = src[2], v3 = src[3];
    const int jp = (t >> 2) * 8 + (t & 3) * 2;  // j'*8 + p0 (even)
    const float* lo = (const float*)&v0;  // k=0..3, p0   (v1: k=4..7)
    const float* hi = (const float*)&v2;  // k=0..3, p0+1 (v3: k=4..7)
#pragma unroll
    for (int k = 0; k < 4; ++k) {
      unsigned int pk =
          (unsigned int)f2bf(lo[k]) | ((unsigned int)f2bf(hi[k]) << 16);
      *(unsigned int*)&lT[k][jp] = pk;
    }
    lo = (const float*)&v1;
    hi = (const float*)&v3;
#pragma unroll
    for (int k = 0; k < 4; ++k) {
      unsigned int pk =
          (unsigned int)f2bf(lo[k]) | ((unsigned int)f2bf(hi[k]) << 16);
      *(unsigned int*)&lT[k + 4][jp] = pk;
    }
    __syncthreads();
    const int r = t >> 5, c = t & 31;  // 32B/thread, 1KB contiguous runs
    const uint4* s = (const uint4*)&lT[r][c * 16];
    uint4* d = (uint4*)(bt + (size_t)(i * 8 + r) * K_DIM + jg * 512 + c * 16);
    d[0] = s[0];
    d[1] = s[1];
  } else {
    int g = (bid - 4096) * 256 + t;  // [0, 262144); 8 elements each
    const float4* xi = (const float4*)x;
    float4 a = xi[g * 2];
    float4 b = xi[g * 2 + 1];
    __attribute__((aligned(16))) unsigned short o[8] = {
        f2bf(a.x), f2bf(a.y), f2bf(a.z), f2bf(a.w),
        f2bf(b.x), f2bf(b.y), f2bf(b.z), f2bf(b.w)};
    *(uint4*)(abf + (size_t)g * 8) = *(const uint4*)o;
  }
}

__device__ inline void gld16(const void* g, void* l) {
  __builtin_amdgcn_global_load_lds(
      (const __attribute__((address_space(1))) unsigned int*)g,
      (__attribute__((address_space(3))) unsigned int*)l, 16, 0, 0);
}

// Tile 64M x 64N, BK=32, full K=4096 per block. 256 threads = 4 waves,
// wave-tile 32M x 32N (2x2 acc). LDS: A 64x32 (4KB) + B 64x32 (4KB) per
// buffer, dbuf = 16KB. grid 64x8 = 512 blocks = 2/CU (cross-block overlap).
// Epilogue: out = acc + bias directly (sole writer per tile, no split-K).
__global__ __launch_bounds__(256) void gemm_kernel(
    const unsigned short* __restrict__ A, const unsigned short* __restrict__ Bt,
    const float* __restrict__ bias, float* __restrict__ out) {
  __shared__ __align__(16) char lds[2][8 * 1024];
  const int t = threadIdx.x;
  const int n0 = blockIdx.x * 64;
  const int m0 = blockIdx.y * 64;
  const int w = t >> 6;
  const int lane = t & 63;
  const int wr = w >> 1;     // 0..1 -> 32 M-rows
  const int wc = w & 1;      // 0..1 -> 32 N-cols
  const int lrow = lane & 15;
  const int kb = lane >> 4;  // k-block 0..3 (8 bf16 each)

  f32x4 acc[2][2] = {};

  // staging: each thread 1 A-seg + 1 B-seg of 16B: row t>>2, col (t&3)*8.
  // LDS dest = wave-uniform base + lane*16 == (seg*4096) + t*16.
  const int srow = t >> 2;       // 0..63
  const int scol = (t & 3) * 8;  // element col (16B-aligned)
  const size_t aOff = (size_t)(m0 + srow) * K_DIM + scol;
  const size_t bOff = (size_t)(n0 + srow) * K_DIM + scol;

  auto issue = [&](int it) {
    char* buf = lds[it & 1];
    gld16(A + aOff + it * 32, buf + t * 16);
    gld16(Bt + bOff + it * 32, buf + 4096 + t * 16);
  };

  issue(0);
  for (int it = 0; it < NIT; ++it) {
    __syncthreads();
    if (it + 1 < NIT) issue(it + 1);
    const unsigned short* cA = (const unsigned short*)lds[it & 1];
    const unsigned short* cB = cA + 2048;  // +4KB

    bf16x8 af[2], bfr[2];
#pragma unroll
    for (int mt = 0; mt < 2; ++mt)
      af[mt] = *(const bf16x8*)(cA + (wr * 32 + mt * 16 + lrow) * 32 + kb * 8);
#pragma unroll
    for (int nt = 0; nt < 2; ++nt)
      bfr[nt] = *(const bf16x8*)(cB + (wc * 32 + nt * 16 + lrow) * 32 + kb * 8);
#pragma unroll
    for (int mt = 0; mt < 2; ++mt)
#pragma unroll
      for (int nt = 0; nt < 2; ++nt)
        acc[mt][nt] = __builtin_amdgcn_mfma_f32_16x16x32_bf16(
            af[mt], bfr[nt], acc[mt][nt], 0, 0, 0);
  }

  // C/D layout (verified m89/m91): col = lane&15, row = (lane>>4)*4 + reg
#pragma unroll
  for (int mt = 0; mt < 2; ++mt) {
    const int gmb = m0 + wr * 32 + mt * 16 + kb * 4;
#pragma unroll
    for (int nt = 0; nt < 2; ++nt) {
      const int gn = n0 + wc * 32 + nt * 16 + lrow;
      const float bv = bias[gn];
#pragma unroll
      for (int r = 0; r < 4; ++r)
        out[(size_t)(gmb + r) * N_DIM + gn] = acc[mt][nt][r] + bv;
    }
  }
}

extern "C" void kernel_launch(void* const* d_in, const int* in_sizes, int n_in,
                              void* d_out, int out_size, void* d_ws,
                              size_t ws_size, hipStream_t stream) {
  const float* x = (const float*)d_in[0];     // [512, 4096]
  const float* w = (const float*)d_in[1];     // [512, 512, 8, 8]
  const float* bias = (const float*)d_in[2];  // [512, 8] -> flat 4096 = col n
  float* out = (float*)d_out;                 // [512, 4096]

  unsigned short* abf = (unsigned short*)d_ws;       // [0, 4MB) bf16 A
  unsigned short* bt = abf + (size_t)M_DIM * K_DIM;  // [4MB, 36MB) bf16 B^T
  (void)ws_size;  // needs 36MB; harness provides >=68MB (prior rounds)

  prep_kernel<<<5120, 256, 0, stream>>>(x, w, abf, bt);

  dim3 grid(N_DIM / 64, M_DIM / 64);  // 64 x 8 = 512 blocks, 2/CU
  gemm_kernel<<<grid, 256, 0, stream>>>(abf, bt, bias, out);
}

// Round 5
// 137.687 us; speedup vs baseline: 1.0439x; 1.0439x over previous
//
#include <hip/hip_runtime.h>
#include <stdint.h>

// OctonionLinear == GEMM: out[b, i*8+k] = sum_{j,p} x[b, j*8+p] * W[i,j,p,k] + bias[i,k]
// M=512, N=4096, K=4096, fp32 in/out, bf16 MFMA.
// R12 = R10 (best verified, 138.87us) + 2-way LDS slot-rotation swizzle.
//  R11 profile: gemm latency/LDS-bound (MfmaUtil 14%, HBM 12%), with
//  SQ_LDS_BANK_CONFLICT=4.19M cyc (~6.8us): [row][32k] 64-B rows make every
//  ds_read_b128 fragment an 8-way conflict (bank = f(row&1, kb) only).
//  Fix: LDS slot l of row r holds global k-chunk g where l=(g+(r>>1))&3.
//  - staging: global_load_lds dest stays LINEAR (rule #21); only per-thread
//    global source column is permuted within each row's 64B quad -> same
//    coalescing.
//  - read: slot=(kb+(lrow>>1))&3 -> lanes tile all 32 banks, exactly 2-way
//    (free, m136).
//  Structure otherwise identical to R10: KSPLIT=4, 128x128 tile, 4 waves of
//  64x64 (4x4 acc, 16 MFMA + 8 b128-reads per barrier), 32KB dbuf,
//  part[4] + reduce epilogue, atomic fallback if ws too small.

#define M_DIM 512
#define N_DIM 4096
#define K_DIM 4096
#define KSPLIT 4
#define KC (K_DIM / KSPLIT)                    // 1024
#define NIT (KC / 32)                          // 32
#define PART_ELEMS (M_DIM * N_DIM)             // 2097152 floats per z-slice

typedef __bf16 bf16x8 __attribute__((ext_vector_type(8)));
typedef float f32x4 __attribute__((ext_vector_type(4)));

__device__ inline unsigned short f2bf(float f) {
  union { float f; unsigned int u; } v;
  v.f = f;
  unsigned int u = v.u;
  unsigned int r = (u + 0x7fffu + ((u >> 16) & 1u)) >> 16;  // RNE
  return (unsigned short)r;
}

// blocks [0,4096): W transpose+convert -> bt[nn][kk], coalesced 16KB chunks.
// blocks [4096,5120): x convert -> abf, 8 el/thread.
// blocks [5120,7168): out = bias broadcast (ONLY launched in atomic path).
__global__ __launch_bounds__(256) void prep_kernel(
    const float* __restrict__ x, const float* __restrict__ w,
    const float* __restrict__ bias, unsigned short* __restrict__ abf,
    unsigned short* __restrict__ bt, float* __restrict__ out) {
  const int bid = blockIdx.x;
  const int t = threadIdx.x;
  if (bid < 4096) {
    __shared__ __align__(16) unsigned short lT[8][512];  // [k][j'*8+p], 8KB
    const int i = bid >> 3;
    const int jg = bid & 7;
    const float4* src =
        (const float4*)(w + (size_t)i * 32768 + jg * 4096 + t * 16);
    float4 v0 = src[0], v1 = src[1], v2 = src[2], v3 = src[3];
    const int jp = (t >> 2) * 8 + (t & 3) * 2;  // j'*8 + p0 (even)
    const float* lo = (const float*)&v0;  // k=0..3, p0   (v1: k=4..7)
    const float* hi = (const float*)&v2;  // k=0..3, p0+1 (v3: k=4..7)
#pragma unroll
    for (int k = 0; k < 4; ++k) {
      unsigned int pk =
          (unsigned int)f2bf(lo[k]) | ((unsigned int)f2bf(hi[k]) << 16);
      *(unsigned int*)&lT[k][jp] = pk;
    }
    lo = (const float*)&v1;
    hi = (const float*)&v3;
#pragma unroll
    for (int k = 0; k < 4; ++k) {
      unsigned int pk =
          (unsigned int)f2bf(lo[k]) | ((unsigned int)f2bf(hi[k]) << 16);
      *(unsigned int*)&lT[k + 4][jp] = pk;
    }
    __syncthreads();
    const int r = t >> 5, c = t & 31;  // 32B/thread, 1KB contiguous runs
    const uint4* s = (const uint4*)&lT[r][c * 16];
    uint4* d = (uint4*)(bt + (size_t)(i * 8 + r) * K_DIM + jg * 512 + c * 16);
    d[0] = s[0];
    d[1] = s[1];
  } else if (bid < 5120) {
    int g = (bid - 4096) * 256 + t;  // [0, 262144); 8 elements each
    const float4* xi = (const float4*)x;
    float4 a = xi[g * 2];
    float4 b = xi[g * 2 + 1];
    __attribute__((aligned(16))) unsigned short o[8] = {
        f2bf(a.x), f2bf(a.y), f2bf(a.z), f2bf(a.w),
        f2bf(b.x), f2bf(b.y), f2bf(b.z), f2bf(b.w)};
    *(uint4*)(abf + (size_t)g * 8) = *(const uint4*)o;
  } else {
    int g = (bid - 5120) * 256 + t;  // [0, 524288); 4 elements each
    int el = g * 4;
    int col = el & (N_DIM - 1);
    *(float4*)(out + el) = *(const float4*)(bias + col);
  }
}

__device__ inline void gld16(const void* g, void* l) {
  __builtin_amdgcn_global_load_lds(
      (const __attribute__((address_space(1))) unsigned int*)g,
      (__attribute__((address_space(3))) unsigned int*)l, 16, 0, 0);
}

// Tile 128M x 128N, BK=32, 256 threads = 4 waves, wave-tile 64M x 64N (4x4).
// LDS: A 128x32 (8KB) + B 128x32 (8KB) per buffer, dbuf = 32KB.
// Swizzled: LDS row r slot l (16B) holds global k-chunk g, l=(g+(r>>1))&3.
__global__ __launch_bounds__(256) void gemm_kernel(
    const unsigned short* __restrict__ A, const unsigned short* __restrict__ Bt,
    float* __restrict__ out, float* __restrict__ part, int use_atomic) {
  __shared__ __align__(16) char lds[2][16 * 1024];
  const int t = threadIdx.x;
  const int n0 = blockIdx.x * 128;
  const int m0 = blockIdx.y * 128;
  const int z = blockIdx.z;
  const int kc0 = z * KC;
  const int w = t >> 6;
  const int lane = t & 63;
  const int wr = w >> 1;     // 0..1 -> 64 M-rows
  const int wc = w & 1;      // 0..1 -> 64 N-cols
  const int lrow = lane & 15;
  const int kb = lane >> 4;  // k-block 0..3 (8 bf16 each)
  // swizzled read slot: lane-constant, 2-way bank aliasing (free)
  const int kslot = (kb + (lrow >> 1)) & 3;

  f32x4 acc[4][4] = {};

  // staging: thread t -> LDS row r=t>>2 (within seg), linear slot l=t&3.
  // source global k-chunk g = (l - (r>>1)) & 3; (r>>1)&3 == (t>>3)&3 for both
  // segs (seg1 adds 64 rows = 32 to r>>1, 32%4==0).
  const int srow = t >> 2;  // 0..63
  const int gslot = ((t & 3) - ((t >> 3) & 3)) & 3;
  const int scol = gslot * 8;  // element col (16B-aligned)
  const size_t aOff0 = (size_t)(m0 + srow) * K_DIM + kc0 + scol;
  const size_t aOff1 = aOff0 + (size_t)64 * K_DIM;
  const size_t bOff0 = (size_t)(n0 + srow) * K_DIM + kc0 + scol;
  const size_t bOff1 = bOff0 + (size_t)64 * K_DIM;

  auto issue = [&](int it) {
    char* buf = lds[it & 1];
    gld16(A + aOff0 + it * 32, buf + t * 16);
    gld16(A + aOff1 + it * 32, buf + 4096 + t * 16);
    gld16(Bt + bOff0 + it * 32, buf + 8192 + t * 16);
    gld16(Bt + bOff1 + it * 32, buf + 12288 + t * 16);
  };

  issue(0);
  for (int it = 0; it < NIT; ++it) {
    __syncthreads();
    if (it + 1 < NIT) issue(it + 1);
    const unsigned short* cA = (const unsigned short*)lds[it & 1];
    const unsigned short* cB = cA + 4096;  // +8KB

    bf16x8 af[4], bfr[4];
#pragma unroll
    for (int mt = 0; mt < 4; ++mt)
      af[mt] =
          *(const bf16x8*)(cA + (wr * 64 + mt * 16 + lrow) * 32 + kslot * 8);
#pragma unroll
    for (int nt = 0; nt < 4; ++nt)
      bfr[nt] =
          *(const bf16x8*)(cB + (wc * 64 + nt * 16 + lrow) * 32 + kslot * 8);
#pragma unroll
    for (int mt = 0; mt < 4; ++mt)
#pragma unroll
      for (int nt = 0; nt < 4; ++nt)
        acc[mt][nt] = __builtin_amdgcn_mfma_f32_16x16x32_bf16(
            af[mt], bfr[nt], acc[mt][nt], 0, 0, 0);
  }

  // C/D layout (verified m89/m91): col = lane&15, row = (lane>>4)*4 + reg
#pragma unroll
  for (int mt = 0; mt < 4; ++mt) {
    const int gmb = m0 + wr * 64 + mt * 16 + kb * 4;
#pragma unroll
    for (int nt = 0; nt < 4; ++nt) {
      const int gn = n0 + wc * 64 + nt * 16 + lrow;
      if (use_atomic) {
#pragma unroll
        for (int r = 0; r < 4; ++r)
          atomicAdd(out + (size_t)(gmb + r) * N_DIM + gn, acc[mt][nt][r]);
      } else {
        float* p = part + (size_t)z * PART_ELEMS;
#pragma unroll
        for (int r = 0; r < 4; ++r)
          p[(size_t)(gmb + r) * N_DIM + gn] = acc[mt][nt][r];
      }
    }
  }
}

// out = sum_z part[z] + bias ; 2048 blocks x 256 thr x 1 float4
__global__ __launch_bounds__(256) void reduce_kernel(
    const float* __restrict__ part, const float* __restrict__ bias,
    float* __restrict__ out) {
  const int g = blockIdx.x * 256 + threadIdx.x;  // [0, 524288)
  const float4* p = (const float4*)part;
  const float4* b4 = (const float4*)bias;
  const int Q = PART_ELEMS / 4;  // 524288
  float4 s0 = p[g];
  float4 s1 = p[g + Q];
  float4 s2 = p[g + 2 * Q];
  float4 s3 = p[g + 3 * Q];
  float4 bb = b4[g & (N_DIM / 4 - 1)];
  float4 r;
  r.x = s0.x + s1.x + s2.x + s3.x + bb.x;
  r.y = s0.y + s1.y + s2.y + s3.y + bb.y;
  r.z = s0.z + s1.z + s2.z + s3.z + bb.z;
  r.w = s0.w + s1.w + s2.w + s3.w + bb.w;
  ((float4*)out)[g] = r;
}

extern "C" void kernel_launch(void* const* d_in, const int* in_sizes, int n_in,
                              void* d_out, int out_size, void* d_ws,
                              size_t ws_size, hipStream_t stream) {
  const float* x = (const float*)d_in[0];     // [512, 4096]
  const float* w = (const float*)d_in[1];     // [512, 512, 8, 8]
  const float* bias = (const float*)d_in[2];  // [512, 8]
  float* out = (float*)d_out;                 // [512, 4096]

  unsigned short* abf = (unsigned short*)d_ws;       // [0, 4MB) bf16 A
  unsigned short* bt = abf + (size_t)M_DIM * K_DIM;  // [4MB, 36MB) bf16 B^T
  float* part = (float*)((char*)d_ws + 36u * 1024 * 1024);  // [36MB, 68MB)

  const bool have_ws = ws_size >= 68ull * 1024 * 1024;
  const int use_atomic = have_ws ? 0 : 1;

  // bias-init segment only needed for the atomic path
  prep_kernel<<<use_atomic ? 7168 : 5120, 256, 0, stream>>>(x, w, bias, abf,
                                                            bt, out);

  dim3 grid(N_DIM / 128, M_DIM / 128, KSPLIT);  // 32 x 4 x 4 = 512 blocks
  gemm_kernel<<<grid, 256, 0, stream>>>(abf, bt, out, part, use_atomic);

  if (!use_atomic)
    reduce_kernel<<<PART_ELEMS / 4 / 256, 256, 0, stream>>>(part, bias, out);
}